// Round 2
// baseline (763.838 us; speedup 1.0000x reference)
//
#include <hip/hip_runtime.h>
#include <hip/hip_bf16.h>
#include <stdint.h>

typedef unsigned short ushort_t;
typedef __bf16 bf16x8 __attribute__((ext_vector_type(8)));
typedef float    f32x4 __attribute__((ext_vector_type(4)));
typedef unsigned short us4 __attribute__((ext_vector_type(4)));

#define QK_SCALE 0.12751744f   /* log2(e) / sqrt(128) : folded into Q so softmax uses exp2 */
#define NEG_BIG  -1e30f

__device__ __forceinline__ unsigned short f2bf(float f) {
    union { float f; unsigned int u; } v; v.f = f;
    unsigned int u = v.u;
    return (unsigned short)((u + 0x7FFFu + ((u >> 16) & 1u)) >> 16);  // RNE
}

// async global->LDS, 16B per lane. LDS dest is wave-uniform base + lane*16.
__device__ __forceinline__ void gload16(const void* g, void* l) {
    __builtin_amdgcn_global_load_lds(
        (__attribute__((address_space(1))) void*)(uintptr_t)g,
        (__attribute__((address_space(3))) void*)(uint32_t)(uintptr_t)l,
        16, 0, 0);
}

// ---------------- prep kernels ----------------

__global__ __launch_bounds__(256) void cvt_bf16_kernel(
    const float4* __restrict__ in, us4* __restrict__ out, int n4) {
    int i = blockIdx.x * 256 + threadIdx.x;
    if (i >= n4) return;
    float4 v = in[i];
    us4 o; o[0] = f2bf(v.x); o[1] = f2bf(v.y); o[2] = f2bf(v.z); o[3] = f2bf(v.w);
    out[i] = o;
}

// in [R][C] fp32  ->  out [C][R] bf16   (64x64 LDS tile transpose)
__global__ __launch_bounds__(256) void transpose_bf16(
    const float* __restrict__ in, ushort_t* __restrict__ out, int R, int C) {
    __shared__ float t[64][65];
    int c0 = blockIdx.x * 64, r0 = blockIdx.y * 64;
    int cc = threadIdx.x & 63, rr = threadIdx.x >> 6;
#pragma unroll
    for (int i = 0; i < 16; ++i) {
        int r = i * 4 + rr;
        t[r][cc] = in[(size_t)(r0 + r) * C + c0 + cc];
    }
    __syncthreads();
#pragma unroll
    for (int i = 0; i < 16; ++i) {
        int r = i * 4 + rr;
        out[(size_t)(c0 + r) * R + r0 + cc] = f2bf(t[cc][r]);
    }
}

// rope table: [L][64] of (cos, sin)
__global__ __launch_bounds__(256) void rope_table_kernel(float2* __restrict__ rope) {
    int i = blockIdx.x * 256 + threadIdx.x;     // L*64 = 131072 exactly
    int l = i >> 6, j = i & 63;
    float inv = exp2f((float)j * -0.20762050593046f);  // 10000^(-j/64)
    float f = (float)l * inv;
    rope[i] = make_float2(cosf(f), sinf(f));
}

// ---------------- GEMM:  C[M][N] = A[M][K] * Bt[N][K]^T  (bf16 in, fp32 acc) ----------------
// 128x128 tile, BK=64, 256 threads (4 waves), global_load_lds w/ pre-swizzled source,
// XOR-swizzled ds_read_b128 ((row&7)<<4), 2-barrier K loop.
// EPI 0: plain fp32 C write.   EPI 1: qkv epilogue (rope on q/k, transpose on v).

template <int EPI>
__global__ __launch_bounds__(256, 2)
void gemm_bt(const ushort_t* __restrict__ A, const ushort_t* __restrict__ Bt,
             int M, int N, int K,
             float* __restrict__ C,
             ushort_t* __restrict__ Qb, ushort_t* __restrict__ Kb,
             ushort_t* __restrict__ Vt, const float2* __restrict__ rope) {
    constexpr int MI = (EPI == 1) ? 2 : 4;
    constexpr int NI = (EPI == 1) ? 8 : 4;

    __shared__ __attribute__((aligned(16))) ushort_t ldsA[128 * 64];
    __shared__ __attribute__((aligned(16))) ushort_t ldsB[128 * 64];
    char* ldsAc = (char*)ldsA;
    char* ldsBc = (char*)ldsB;

    const int tid  = threadIdx.x;
    const int lane = tid & 63, wid = tid >> 6;
    const int lr = lane & 15, lg = lane >> 4;

    const int nbn = N >> 7;
    const int nwg = gridDim.x;
    const int bid = blockIdx.x;
    const int wg  = (bid & 7) * (nwg >> 3) + (bid >> 3);   // XCD-contiguous chunks
    const int bm  = wg / nbn, bn = wg % nbn;

    const int arow0 = (EPI == 1) ? wid * 32 : (wid >> 1) * 64;
    const int bcol0 = (EPI == 1) ? 0        : (wid & 1) * 64;

    // staging: chunk r covers rows [r*32, r*32+32); lane's 16B block, source pre-swizzled
    const int colb = ((tid & 7) << 4) ^ (((tid >> 3) & 7) << 4);
    const int rowi = tid >> 3;                       // 0..31
    const char* Ap = (const char*)A + ((size_t)(bm * 128 + rowi) * K) * 2 + colb;
    const char* Bp = (const char*)Bt + ((size_t)(bn * 128 + rowi) * K) * 2 + colb;
    const size_t rstr = (size_t)32 * K * 2;
    char* ldA = ldsAc + wid * 1024;
    char* ldB = ldsBc + wid * 1024;

    f32x4 acc[MI][NI];
#pragma unroll
    for (int i = 0; i < MI; ++i)
#pragma unroll
        for (int j = 0; j < NI; ++j) acc[i][j] = (f32x4){0.f, 0.f, 0.f, 0.f};

    for (int k0 = 0; k0 < K; k0 += 64) {
#pragma unroll
        for (int r = 0; r < 4; ++r) {
            gload16(Ap + r * rstr + (size_t)k0 * 2, ldA + r * 4096);
            gload16(Bp + r * rstr + (size_t)k0 * 2, ldB + r * 4096);
        }
        __syncthreads();
#pragma unroll
        for (int kk = 0; kk < 2; ++kk) {
            bf16x8 af[MI], bfv[NI];
#pragma unroll
            for (int mi = 0; mi < MI; ++mi) {
                int row = arow0 + mi * 16 + lr;
                int off = (row << 7) + kk * 64 + lg * 16;
                off ^= (row & 7) << 4;
                af[mi] = *(const bf16x8*)(ldsAc + off);
            }
#pragma unroll
            for (int ni = 0; ni < NI; ++ni) {
                int row = bcol0 + ni * 16 + lr;
                int off = (row << 7) + kk * 64 + lg * 16;
                off ^= (row & 7) << 4;
                bfv[ni] = *(const bf16x8*)(ldsBc + off);
            }
#pragma unroll
            for (int mi = 0; mi < MI; ++mi)
#pragma unroll
                for (int ni = 0; ni < NI; ++ni)
                    acc[mi][ni] = __builtin_amdgcn_mfma_f32_16x16x32_bf16(
                        af[mi], bfv[ni], acc[mi][ni], 0, 0, 0);
        }
        __syncthreads();
    }

    if constexpr (EPI == 0) {
#pragma unroll
        for (int mi = 0; mi < MI; ++mi) {
            int gr0 = bm * 128 + arow0 + mi * 16 + lg * 4;
#pragma unroll
            for (int ni = 0; ni < NI; ++ni) {
                int gc = bn * 128 + bcol0 + ni * 16 + lr;
#pragma unroll
                for (int r = 0; r < 4; ++r)
                    C[(size_t)(gr0 + r) * N + gc] = acc[mi][ni][r];
            }
        }
    } else {
        // one block column == one (which, head): N layout is [3][H=16][D=128]
        const int which = bn >> 4, h = bn & 15;
#pragma unroll
        for (int mi = 0; mi < MI; ++mi) {
            int gr0 = bm * 128 + arow0 + mi * 16 + lg * 4;   // = b*L + l0 (4 consecutive l)
            int b = gr0 >> 11, l0 = gr0 & 2047;
            if (which == 2) {                                 // V -> [BH][D][L] (transposed)
#pragma unroll
                for (int ni = 0; ni < NI; ++ni) {
                    int d = ni * 16 + lr;
                    us4 pk;
#pragma unroll
                    for (int r = 0; r < 4; ++r) pk[r] = f2bf(acc[mi][ni][r]);
                    *(us4*)(Vt + ((size_t)(b * 16 + h) * 128 + d) * 2048 + l0) = pk;
                }
            } else {                                          // Q/K: rope, -> [BH][L][D]
                ushort_t* dst = (which == 0) ? Qb : Kb;
                const float sc = (which == 0) ? QK_SCALE : 1.0f;
#pragma unroll
                for (int ni = 0; ni < 4; ++ni) {
                    int j = ni * 16 + lr;                     // d < 64 ; pair at d+64 = frag ni+4
#pragma unroll
                    for (int r = 0; r < 4; ++r) {
                        float2 cs = rope[(size_t)(l0 + r) * 64 + j];
                        float x1 = acc[mi][ni][r], x2 = acc[mi][ni + 4][r];
                        size_t base = ((size_t)(b * 16 + h) * 2048 + (l0 + r)) * 128;
                        dst[base + j]      = f2bf((x1 * cs.x - x2 * cs.y) * sc);
                        dst[base + j + 64] = f2bf((x2 * cs.x + x1 * cs.y) * sc);
                    }
                }
            }
        }
    }
}

// ---------------- causal flash attention ----------------
// Q,K: [BH][L][128] bf16 (Q pre-scaled by log2e/sqrt(D)); V: [BH][128][L] bf16
// out AO: [B][L][H*128] bf16.
// 512 blocks: (head, pair p). Each wave handles its 32-row slice of q-tile p,
// then of q-tile 15-p -> ~33 k-tiles per wave everywhere (no causal tail).
// V fragments prefetched into registers before softmax to hide global latency.

__global__ __launch_bounds__(256, 2)
void attn_fwd(const ushort_t* __restrict__ Qb, const ushort_t* __restrict__ Kb,
              const ushort_t* __restrict__ Vt, ushort_t* __restrict__ AO) {
    constexpr int L = 2048;
    __shared__ __attribute__((aligned(16))) ushort_t P_lds[4][32 * 64];

    const int tid  = threadIdx.x;
    const int lane = tid & 63, wid = tid >> 6;
    const int lr = lane & 15, lg = lane >> 4;

    // grid remap: 512 blocks; each XCD (bid&7) owns 8 consecutive heads
    const int bid  = blockIdx.x;
    const int slot = bid >> 3;                 // 0..63
    const int head = (bid & 7) * 8 + (slot >> 3);
    const int pr   = slot & 7;                 // pair index 0..7

    const ushort_t* Qh = Qb + (size_t)head * L * 128;
    const ushort_t* Kh = Kb + (size_t)head * L * 128;
    const ushort_t* Vh = Vt + (size_t)head * 128 * L;
    char* Pw = (char*)&P_lds[wid][0];
    const int b = head >> 4, h = head & 15;

    for (int ph = 0; ph < 2; ++ph) {
        const int qt  = ph ? (15 - pr) : pr;
        const int q0w = qt * 128 + wid * 32;

        // Q fragments hoisted to registers
        bf16x8 qa[2][4];
#pragma unroll
        for (int mi = 0; mi < 2; ++mi)
#pragma unroll
            for (int kk = 0; kk < 4; ++kk)
                qa[mi][kk] = *(const bf16x8*)(Qh + (size_t)(q0w + mi * 16 + lr) * 128 + kk * 32 + lg * 8);

        f32x4 o[2][8];
        float m_[2][4], l_[2][4];
#pragma unroll
        for (int mi = 0; mi < 2; ++mi) {
#pragma unroll
            for (int ni = 0; ni < 8; ++ni) o[mi][ni] = (f32x4){0.f, 0.f, 0.f, 0.f};
#pragma unroll
            for (int r = 0; r < 4; ++r) { m_[mi][r] = -__builtin_inff(); l_[mi][r] = 0.f; }
        }

        const int ntile = ((q0w + 31) >> 6) + 1;
        for (int t = 0; t < ntile; ++t) {
            const int k0 = t << 6;
            f32x4 s[2][4];
#pragma unroll
            for (int mi = 0; mi < 2; ++mi)
#pragma unroll
                for (int ni = 0; ni < 4; ++ni) s[mi][ni] = (f32x4){0.f, 0.f, 0.f, 0.f};

            // S = Q K^T  (K fragments straight from global; L2-resident)
#pragma unroll
            for (int kk = 0; kk < 4; ++kk) {
                bf16x8 kf[4];
#pragma unroll
                for (int ni = 0; ni < 4; ++ni)
                    kf[ni] = *(const bf16x8*)(Kh + (size_t)(k0 + ni * 16 + lr) * 128 + kk * 32 + lg * 8);
#pragma unroll
                for (int mi = 0; mi < 2; ++mi)
#pragma unroll
                    for (int ni = 0; ni < 4; ++ni)
                        s[mi][ni] = __builtin_amdgcn_mfma_f32_16x16x32_bf16(qa[mi][kk], kf[ni], s[mi][ni], 0, 0, 0);
            }

            // prefetch V fragments for this tile NOW -- latency hides under softmax
            bf16x8 vf[8][2];
#pragma unroll
            for (int ni = 0; ni < 8; ++ni)
#pragma unroll
                for (int kk = 0; kk < 2; ++kk)
                    vf[ni][kk] = *(const bf16x8*)(Vh + (size_t)(ni * 16 + lr) * L + k0 + kk * 32 + lg * 8);

            if (k0 + 63 > q0w) {   // diagonal tile: causal mask
#pragma unroll
                for (int mi = 0; mi < 2; ++mi)
#pragma unroll
                    for (int ni = 0; ni < 4; ++ni)
#pragma unroll
                        for (int r = 0; r < 4; ++r) {
                            int qg = q0w + mi * 16 + lg * 4 + r;
                            int kg = k0 + ni * 16 + lr;
                            s[mi][ni][r] = (kg > qg) ? NEG_BIG : s[mi][ni][r];
                        }
            }

            float alpha[2][4];
#pragma unroll
            for (int mi = 0; mi < 2; ++mi) {
                float t4[4];
#pragma unroll
                for (int r = 0; r < 4; ++r)
                    t4[r] = fmaxf(fmaxf(s[mi][0][r], s[mi][1][r]), fmaxf(s[mi][2][r], s[mi][3][r]));
#pragma unroll
                for (int msk = 1; msk <= 8; msk <<= 1)
#pragma unroll
                    for (int r = 0; r < 4; ++r) t4[r] = fmaxf(t4[r], __shfl_xor(t4[r], msk, 64));
#pragma unroll
                for (int r = 0; r < 4; ++r) {
                    float mn = fmaxf(m_[mi][r], t4[r]);
                    alpha[mi][r] = exp2f(m_[mi][r] - mn);
                    m_[mi][r] = mn;
                }
                float rs[4] = {0.f, 0.f, 0.f, 0.f};
#pragma unroll
                for (int ni = 0; ni < 4; ++ni)
#pragma unroll
                    for (int r = 0; r < 4; ++r) {
                        float p = exp2f(s[mi][ni][r] - m_[mi][r]);
                        rs[r] += p;
                        int row32 = mi * 16 + lg * 4 + r;
                        int off = (row32 << 7) + ((ni * 16 + lr) << 1);
                        off ^= (row32 & 7) << 4;
                        *(ushort_t*)(Pw + off) = f2bf(p);
                    }
#pragma unroll
                for (int msk = 1; msk <= 8; msk <<= 1)
#pragma unroll
                    for (int r = 0; r < 4; ++r) rs[r] += __shfl_xor(rs[r], msk, 64);
#pragma unroll
                for (int r = 0; r < 4; ++r) l_[mi][r] = l_[mi][r] * alpha[mi][r] + rs[r];
            }

            // rescale O
#pragma unroll
            for (int mi = 0; mi < 2; ++mi)
#pragma unroll
                for (int ni = 0; ni < 8; ++ni)
#pragma unroll
                    for (int r = 0; r < 4; ++r) o[mi][ni][r] *= alpha[mi][r];

            // P (A-layout, swizzled) from LDS ; O += P V  (compiler orders LDS RAW)
            bf16x8 pa[2][2];
#pragma unroll
            for (int mi2 = 0; mi2 < 2; ++mi2)
#pragma unroll
                for (int kk = 0; kk < 2; ++kk) {
                    int row = mi2 * 16 + lr;
                    int off = (row << 7) + kk * 64 + lg * 16;
                    off ^= (row & 7) << 4;
                    pa[mi2][kk] = *(const bf16x8*)(Pw + off);
                }
#pragma unroll
            for (int ni = 0; ni < 8; ++ni)
#pragma unroll
                for (int kk = 0; kk < 2; ++kk)
#pragma unroll
                    for (int mi2 = 0; mi2 < 2; ++mi2)
                        o[mi2][ni] = __builtin_amdgcn_mfma_f32_16x16x32_bf16(pa[mi2][kk], vf[ni][kk], o[mi2][ni], 0, 0, 0);
        }

        // epilogue: normalize and store [B][L][H*128]
#pragma unroll
        for (int mi = 0; mi < 2; ++mi) {
            float inv[4];
#pragma unroll
            for (int r = 0; r < 4; ++r) inv[r] = 1.f / l_[mi][r];
#pragma unroll
            for (int ni = 0; ni < 8; ++ni)
#pragma unroll
                for (int r = 0; r < 4; ++r) {
                    size_t off = ((size_t)(b * 2048 + q0w + mi * 16 + lg * 4 + r)) * 2048 + h * 128 + ni * 16 + lr;
                    AO[off] = f2bf(o[mi][ni][r] * inv[r]);
                }
        }
    }
}

// ---------------- launcher ----------------

extern "C" void kernel_launch(void* const* d_in, const int* in_sizes, int n_in,
                              void* d_out, int out_size, void* d_ws, size_t ws_size,
                              hipStream_t stream) {
    const float* x    = (const float*)d_in[0];   // [4,2048,2048]
    const float* Wqkv = (const float*)d_in[1];   // [2048,6144]
    const float* Wo   = (const float*)d_in[2];   // [2048,2048]
    float* out = (float*)d_out;                  // [4,2048,2048] fp32

    char* w = (char*)d_ws;
    ushort_t* xb   = (ushort_t*)(w);               // x bf16             33,554,432 B
    ushort_t* W1t  = (ushort_t*)(w + 33554432);    // Wqkv^T bf16        25,165,824 B
    ushort_t* Wot  = (ushort_t*)(w + 58720256);    // Wo^T bf16           8,388,608 B
    ushort_t* Qb   = (ushort_t*)(w + 67108864);    // Q roped [BH][L][D] 33,554,432 B
    ushort_t* Kbf  = (ushort_t*)(w + 100663296);   // K roped [BH][L][D] 33,554,432 B
    ushort_t* Vt   = (ushort_t*)(w + 134217728);   // V^T    [BH][D][L]  33,554,432 B
    ushort_t* AO   = (ushort_t*)(w + 167772160);   // attn out bf16      33,554,432 B
    float2*   rope = (float2*)(w + 201326592);     // [L][64] cos/sin     1,048,576 B
                                                   // total ~202.4 MB

    cvt_bf16_kernel<<<16384, 256, 0, stream>>>((const float4*)x, (us4*)xb, 4194304);
    transpose_bf16<<<dim3(96, 32), 256, 0, stream>>>(Wqkv, W1t, 2048, 6144);
    transpose_bf16<<<dim3(32, 32), 256, 0, stream>>>(Wo, Wot, 2048, 2048);
    rope_table_kernel<<<512, 256, 0, stream>>>(rope);

    // qkv GEMM + fused rope/reshape epilogue
    gemm_bt<1><<<3072, 256, 0, stream>>>(xb, W1t, 8192, 6144, 2048,
                                         nullptr, Qb, Kbf, Vt, rope);
    // causal flash attention (paired q-tiles, balanced)
    attn_fwd<<<512, 256, 0, stream>>>(Qb, Kbf, Vt, AO);
    // output projection
    gemm_bt<0><<<1024, 256, 0, stream>>>(AO, Wot, 8192, 2048, 2048,
                                         out, nullptr, nullptr, nullptr, nullptr);
}

// Round 4
// 637.956 us; speedup vs baseline: 1.1973x; 1.1973x over previous
//
#include <hip/hip_runtime.h>
#include <hip/hip_bf16.h>
#include <stdint.h>

typedef unsigned short ushort_t;
typedef __bf16 bf16x8 __attribute__((ext_vector_type(8)));
typedef float    f32x4 __attribute__((ext_vector_type(4)));
typedef float   f32x16 __attribute__((ext_vector_type(16)));
typedef unsigned short us4 __attribute__((ext_vector_type(4)));
typedef unsigned int ui4 __attribute__((ext_vector_type(4)));

#define QK_SCALE 0.12751744f   /* log2(e) / sqrt(128) : folded into Q so softmax uses exp2 */
#define NEG_BIG  -1e30f

__device__ __forceinline__ unsigned short f2bf(float f) {
    union { float f; unsigned int u; } v; v.f = f;
    unsigned int u = v.u;
    return (unsigned short)((u + 0x7FFFu + ((u >> 16) & 1u)) >> 16);  // RNE
}

__device__ __forceinline__ unsigned int pk2bf(float a, float b) {
    return (unsigned int)f2bf(a) | ((unsigned int)f2bf(b) << 16);   // low = a, high = b
}

// async global->LDS, 16B per lane. LDS dest is wave-uniform base + lane*16.
__device__ __forceinline__ void gload16(const void* g, void* l) {
    __builtin_amdgcn_global_load_lds(
        (__attribute__((address_space(1))) void*)(uintptr_t)g,
        (__attribute__((address_space(3))) void*)(uint32_t)(uintptr_t)l,
        16, 0, 0);
}

// ---------------- prep kernels ----------------

__global__ __launch_bounds__(256) void cvt_bf16_kernel(
    const float4* __restrict__ in, us4* __restrict__ out, int n4) {
    int i = blockIdx.x * 256 + threadIdx.x;
    if (i >= n4) return;
    float4 v = in[i];
    us4 o; o[0] = f2bf(v.x); o[1] = f2bf(v.y); o[2] = f2bf(v.z); o[3] = f2bf(v.w);
    out[i] = o;
}

// in [R][C] fp32  ->  out [C][R] bf16   (64x64 LDS tile transpose)
__global__ __launch_bounds__(256) void transpose_bf16(
    const float* __restrict__ in, ushort_t* __restrict__ out, int R, int C) {
    __shared__ float t[64][65];
    int c0 = blockIdx.x * 64, r0 = blockIdx.y * 64;
    int cc = threadIdx.x & 63, rr = threadIdx.x >> 6;
#pragma unroll
    for (int i = 0; i < 16; ++i) {
        int r = i * 4 + rr;
        t[r][cc] = in[(size_t)(r0 + r) * C + c0 + cc];
    }
    __syncthreads();
#pragma unroll
    for (int i = 0; i < 16; ++i) {
        int r = i * 4 + rr;
        out[(size_t)(c0 + r) * R + r0 + cc] = f2bf(t[cc][r]);
    }
}

// rope table: [L][64] of (cos, sin)
__global__ __launch_bounds__(256) void rope_table_kernel(float2* __restrict__ rope) {
    int i = blockIdx.x * 256 + threadIdx.x;     // L*64 = 131072 exactly
    int l = i >> 6, j = i & 63;
    float inv = exp2f((float)j * -0.20762050593046f);  // 10000^(-j/64)
    float f = (float)l * inv;
    rope[i] = make_float2(cosf(f), sinf(f));
}

// ---------------- GEMM:  C[M][N] = A[M][K] * Bt[N][K]^T  (bf16 in, fp32 acc) ----------------

template <int EPI>
__global__ __launch_bounds__(256, 2)
void gemm_bt(const ushort_t* __restrict__ A, const ushort_t* __restrict__ Bt,
             int M, int N, int K,
             float* __restrict__ C,
             ushort_t* __restrict__ Qb, ushort_t* __restrict__ Kb,
             ushort_t* __restrict__ Vt, const float2* __restrict__ rope) {
    constexpr int MI = (EPI == 1) ? 2 : 4;
    constexpr int NI = (EPI == 1) ? 8 : 4;

    __shared__ __attribute__((aligned(16))) ushort_t ldsA[128 * 64];
    __shared__ __attribute__((aligned(16))) ushort_t ldsB[128 * 64];
    char* ldsAc = (char*)ldsA;
    char* ldsBc = (char*)ldsB;

    const int tid  = threadIdx.x;
    const int lane = tid & 63, wid = tid >> 6;
    const int lr = lane & 15, lg = lane >> 4;

    const int nbn = N >> 7;
    const int nwg = gridDim.x;
    const int bid = blockIdx.x;
    const int wg  = (bid & 7) * (nwg >> 3) + (bid >> 3);   // XCD-contiguous chunks
    const int bm  = wg / nbn, bn = wg % nbn;

    const int arow0 = (EPI == 1) ? wid * 32 : (wid >> 1) * 64;
    const int bcol0 = (EPI == 1) ? 0        : (wid & 1) * 64;

    const int colb = ((tid & 7) << 4) ^ (((tid >> 3) & 7) << 4);
    const int rowi = tid >> 3;                       // 0..31
    const char* Ap = (const char*)A + ((size_t)(bm * 128 + rowi) * K) * 2 + colb;
    const char* Bp = (const char*)Bt + ((size_t)(bn * 128 + rowi) * K) * 2 + colb;
    const size_t rstr = (size_t)32 * K * 2;
    char* ldA = ldsAc + wid * 1024;
    char* ldB = ldsBc + wid * 1024;

    f32x4 acc[MI][NI];
#pragma unroll
    for (int i = 0; i < MI; ++i)
#pragma unroll
        for (int j = 0; j < NI; ++j) acc[i][j] = (f32x4){0.f, 0.f, 0.f, 0.f};

    for (int k0 = 0; k0 < K; k0 += 64) {
#pragma unroll
        for (int r = 0; r < 4; ++r) {
            gload16(Ap + r * rstr + (size_t)k0 * 2, ldA + r * 4096);
            gload16(Bp + r * rstr + (size_t)k0 * 2, ldB + r * 4096);
        }
        __syncthreads();
#pragma unroll
        for (int kk = 0; kk < 2; ++kk) {
            bf16x8 af[MI], bfv[NI];
#pragma unroll
            for (int mi = 0; mi < MI; ++mi) {
                int row = arow0 + mi * 16 + lr;
                int off = (row << 7) + kk * 64 + lg * 16;
                off ^= (row & 7) << 4;
                af[mi] = *(const bf16x8*)(ldsAc + off);
            }
#pragma unroll
            for (int ni = 0; ni < NI; ++ni) {
                int row = bcol0 + ni * 16 + lr;
                int off = (row << 7) + kk * 64 + lg * 16;
                off ^= (row & 7) << 4;
                bfv[ni] = *(const bf16x8*)(ldsBc + off);
            }
#pragma unroll
            for (int mi = 0; mi < MI; ++mi)
#pragma unroll
                for (int ni = 0; ni < NI; ++ni)
                    acc[mi][ni] = __builtin_amdgcn_mfma_f32_16x16x32_bf16(
                        af[mi], bfv[ni], acc[mi][ni], 0, 0, 0);
        }
        __syncthreads();
    }

    if constexpr (EPI == 0) {
#pragma unroll
        for (int mi = 0; mi < MI; ++mi) {
            int gr0 = bm * 128 + arow0 + mi * 16 + lg * 4;
#pragma unroll
            for (int ni = 0; ni < NI; ++ni) {
                int gc = bn * 128 + bcol0 + ni * 16 + lr;
#pragma unroll
                for (int r = 0; r < 4; ++r)
                    C[(size_t)(gr0 + r) * N + gc] = acc[mi][ni][r];
            }
        }
    } else {
        const int which = bn >> 4, h = bn & 15;
#pragma unroll
        for (int mi = 0; mi < MI; ++mi) {
            int gr0 = bm * 128 + arow0 + mi * 16 + lg * 4;   // = b*L + l0 (4 consecutive l)
            int b = gr0 >> 11, l0 = gr0 & 2047;
            if (which == 2) {                                 // V -> [BH][D][L] (transposed)
#pragma unroll
                for (int ni = 0; ni < NI; ++ni) {
                    int d = ni * 16 + lr;
                    us4 pk;
#pragma unroll
                    for (int r = 0; r < 4; ++r) pk[r] = f2bf(acc[mi][ni][r]);
                    *(us4*)(Vt + ((size_t)(b * 16 + h) * 128 + d) * 2048 + l0) = pk;
                }
            } else {                                          // Q/K: rope, -> [BH][L][D]
                ushort_t* dst = (which == 0) ? Qb : Kb;
                const float sc = (which == 0) ? QK_SCALE : 1.0f;
#pragma unroll
                for (int ni = 0; ni < 4; ++ni) {
                    int j = ni * 16 + lr;                     // d < 64 ; pair at d+64 = frag ni+4
#pragma unroll
                    for (int r = 0; r < 4; ++r) {
                        float2 cs = rope[(size_t)(l0 + r) * 64 + j];
                        float x1 = acc[mi][ni][r], x2 = acc[mi][ni + 4][r];
                        size_t base = ((size_t)(b * 16 + h) * 2048 + (l0 + r)) * 128;
                        dst[base + j]      = f2bf((x1 * cs.x - x2 * cs.y) * sc);
                        dst[base + j + 64] = f2bf((x2 * cs.x + x1 * cs.y) * sc);
                    }
                }
            }
        }
    }
}

// ---------------- causal flash attention (swapped-operand, in-register softmax) ----------------
// Q,K: [BH][L][128] bf16 (Q pre-scaled); V^T: [BH][128][L] bf16; AO: [B][L][H*128] bf16.
// One wave (64 thr) per block. Each block: one head, slice pair (sl, 63-sl), 32 q-rows each.
// S^T = mfma32x32x16(K, Q^T): lane owns q = lane&31; 16 of 32 k in regs, partner lane^32 rest.
// Softmax fully in-register (scalar m,l per lane). O^T = mfma(V^T, P^T): col=lane&31=q, so
// rescale is a per-lane scalar multiply. P^T frags assembled via cvt_pk + shfl_xor(32).

__global__ __launch_bounds__(64, 2)
void attn_fwd(const ushort_t* __restrict__ Qb, const ushort_t* __restrict__ Kb,
              const ushort_t* __restrict__ Vt, ushort_t* __restrict__ AO) {
    constexpr int L = 2048;
    const int lane = threadIdx.x;
    const int q_l  = lane & 31;
    const int hi   = lane >> 5;

    // 2048 blocks: head = (bid&7)*8 + ((bid>>3)>>5)  -> all 32 blocks of a head on one XCD
    const int bid  = blockIdx.x;
    const int idx  = bid >> 3;
    const int head = (bid & 7) * 8 + (idx >> 5);
    const int pr   = idx & 31;                  // pair index 0..31

    const ushort_t* Qh = Qb + (size_t)head * L * 128;
    const ushort_t* Kh = Kb + (size_t)head * L * 128;
    const ushort_t* Vh = Vt + (size_t)head * 128 * L;
    const int b = head >> 4, h = head & 15;

    for (int ph = 0; ph < 2; ++ph) {
        const int sl = ph ? (63 - pr) : pr;     // slice 0..63
        const int q0 = sl * 32;

        // Q^T B-frags hoisted: lane holds Q[q0+q_l][slab*16 + hi*8 + 0..7]
        bf16x8 qf[8];
#pragma unroll
        for (int sb = 0; sb < 8; ++sb)
            qf[sb] = *(const bf16x8*)(Qh + (size_t)(q0 + q_l) * 128 + sb * 16 + hi * 8);

        f32x16 o[4];
#pragma unroll
        for (int d0 = 0; d0 < 4; ++d0) o[d0] = (f32x16)(0.f);
        float m_ = -__builtin_inff(), l_ = 0.f;

        const int ntile = sl + 1;
        for (int t = 0; t < ntile; ++t) {
            const int k0 = t * 32;

            // ---- S^T = K * Q^T : A = K rows (32 k), B = Q^T ----
            bf16x8 kf[8];
#pragma unroll
            for (int sb = 0; sb < 8; ++sb)
                kf[sb] = *(const bf16x8*)(Kh + (size_t)(k0 + q_l) * 128 + sb * 16 + hi * 8);
            f32x16 s = (f32x16)(0.f);
#pragma unroll
            for (int sb = 0; sb < 8; ++sb)
                s = __builtin_amdgcn_mfma_f32_32x32x16_bf16(kf[sb], qf[sb], s, 0, 0, 0);

            // causal mask on the diagonal tile: k = k0 + crow(reg,hi), q = q0 + q_l, k0==q0
            if (t == ntile - 1) {
#pragma unroll
                for (int r = 0; r < 16; ++r) {
                    int kk = (r & 3) + 8 * (r >> 2) + 4 * hi;
                    if (kk > q_l) s[r] = NEG_BIG;
                }
            }

            // ---- in-register online softmax (lane owns q-row q0+q_l) ----
            float tmax = s[0];
#pragma unroll
            for (int r = 1; r < 16; ++r) tmax = fmaxf(tmax, s[r]);
            tmax = fmaxf(tmax, __shfl_xor(tmax, 32, 64));     // full 32-k row max

            if (!__all(tmax <= m_ + 8.f)) {                   // defer-max THR=8 (log2 units)
                float mn = fmaxf(m_, tmax);
                float alpha = exp2f(m_ - mn);
                m_ = mn;
                l_ *= alpha;
#pragma unroll
                for (int d0 = 0; d0 < 4; ++d0)
#pragma unroll
                    for (int r = 0; r < 16; ++r) o[d0][r] *= alpha;
            }

            float p[16];
            float rs = 0.f;
#pragma unroll
            for (int r = 0; r < 16; ++r) { p[r] = exp2f(s[r] - m_); rs += p[r]; }
            rs += __shfl_xor(rs, 32, 64);
            l_ += rs;

            // ---- pack P -> bf16 pairs; assemble P^T B-frags via partner exchange ----
            unsigned int pk[8];
#pragma unroll
            for (int i = 0; i < 8; ++i) pk[i] = pk2bf(p[2 * i], p[2 * i + 1]);
            unsigned int po[8];
#pragma unroll
            for (int i = 0; i < 8; ++i) po[i] = __shfl_xor(pk[i], 32, 64);

            bf16x8 pf[2];
#pragma unroll
            for (int ks = 0; ks < 2; ++ks) {
                ui4 dw;
                dw[0] = hi ? po[ks * 4 + 2] : pk[ks * 4 + 0];
                dw[1] = hi ? po[ks * 4 + 3] : pk[ks * 4 + 1];
                dw[2] = hi ? pk[ks * 4 + 2] : po[ks * 4 + 0];
                dw[3] = hi ? pk[ks * 4 + 3] : po[ks * 4 + 1];
                pf[ks] = __builtin_bit_cast(bf16x8, dw);
            }

            // ---- O^T += V^T * P^T : A = V^T rows (d), B = P^T ----
#pragma unroll
            for (int d0 = 0; d0 < 4; ++d0) {
#pragma unroll
                for (int ks = 0; ks < 2; ++ks) {
                    bf16x8 vf = *(const bf16x8*)(Vh + (size_t)(d0 * 32 + q_l) * L + k0 + ks * 16 + hi * 8);
                    o[d0] = __builtin_amdgcn_mfma_f32_32x32x16_bf16(vf, pf[ks], o[d0], 0, 0, 0);
                }
            }
        }

        // ---- epilogue: lane owns q-row q0+q_l entirely; d = d0*32 + (g*8 + hi*4 + 0..3) ----
        const float inv = 1.f / l_;
        const size_t rowbase = ((size_t)(b * 2048 + q0 + q_l)) * 2048 + h * 128;
#pragma unroll
        for (int d0 = 0; d0 < 4; ++d0)
#pragma unroll
            for (int g = 0; g < 4; ++g) {
                us4 v;
#pragma unroll
                for (int r = 0; r < 4; ++r) v[r] = f2bf(o[d0][g * 4 + r] * inv);
                *(us4*)(AO + rowbase + d0 * 32 + g * 8 + hi * 4) = v;
            }
    }
}

// ---------------- launcher ----------------

extern "C" void kernel_launch(void* const* d_in, const int* in_sizes, int n_in,
                              void* d_out, int out_size, void* d_ws, size_t ws_size,
                              hipStream_t stream) {
    const float* x    = (const float*)d_in[0];   // [4,2048,2048]
    const float* Wqkv = (const float*)d_in[1];   // [2048,6144]
    const float* Wo   = (const float*)d_in[2];   // [2048,2048]
    float* out = (float*)d_out;                  // [4,2048,2048] fp32

    char* w = (char*)d_ws;
    ushort_t* xb   = (ushort_t*)(w);               // x bf16             33,554,432 B
    ushort_t* W1t  = (ushort_t*)(w + 33554432);    // Wqkv^T bf16        25,165,824 B
    ushort_t* Wot  = (ushort_t*)(w + 58720256);    // Wo^T bf16           8,388,608 B
    ushort_t* Qb   = (ushort_t*)(w + 67108864);    // Q roped [BH][L][D] 33,554,432 B
    ushort_t* Kbf  = (ushort_t*)(w + 100663296);   // K roped [BH][L][D] 33,554,432 B
    ushort_t* Vt   = (ushort_t*)(w + 134217728);   // V^T    [BH][D][L]  33,554,432 B
    ushort_t* AO   = (ushort_t*)(w + 167772160);   // attn out bf16      33,554,432 B
    float2*   rope = (float2*)(w + 201326592);     // [L][64] cos/sin     1,048,576 B

    cvt_bf16_kernel<<<16384, 256, 0, stream>>>((const float4*)x, (us4*)xb, 4194304);
    transpose_bf16<<<dim3(96, 32), 256, 0, stream>>>(Wqkv, W1t, 2048, 6144);
    transpose_bf16<<<dim3(32, 32), 256, 0, stream>>>(Wo, Wot, 2048, 2048);
    rope_table_kernel<<<512, 256, 0, stream>>>(rope);

    // qkv GEMM + fused rope/reshape epilogue
    gemm_bt<1><<<3072, 256, 0, stream>>>(xb, W1t, 8192, 6144, 2048,
                                         nullptr, Qb, Kbf, Vt, rope);
    // causal flash attention: 64 heads x 32 slice-pairs, one wave each
    attn_fwd<<<2048, 64, 0, stream>>>(Qb, Kbf, Vt, AO);
    // output projection
    gemm_bt<0><<<1024, 256, 0, stream>>>(AO, Wot, 8192, 2048, 2048,
                                         out, nullptr, nullptr, nullptr, nullptr);
}

// Round 5
// 612.950 us; speedup vs baseline: 1.2462x; 1.0408x over previous
//
#include <hip/hip_runtime.h>
#include <hip/hip_bf16.h>
#include <stdint.h>

typedef unsigned short ushort_t;
typedef __bf16 bf16x8 __attribute__((ext_vector_type(8)));
typedef float    f32x4 __attribute__((ext_vector_type(4)));
typedef float   f32x16 __attribute__((ext_vector_type(16)));
typedef unsigned short us4 __attribute__((ext_vector_type(4)));
typedef unsigned int ui4 __attribute__((ext_vector_type(4)));

#define QK_SCALE 0.12751744f   /* log2(e) / sqrt(128) : folded into Q so softmax uses exp2 */
#define NEG_BIG  -1e30f

__device__ __forceinline__ unsigned short f2bf(float f) {
    union { float f; unsigned int u; } v; v.f = f;
    unsigned int u = v.u;
    return (unsigned short)((u + 0x7FFFu + ((u >> 16) & 1u)) >> 16);  // RNE
}

__device__ __forceinline__ unsigned int pk2bf(float a, float b) {
    return (unsigned int)f2bf(a) | ((unsigned int)f2bf(b) << 16);   // low = a, high = b
}

// async global->LDS, 16B per lane. LDS dest is wave-uniform base + lane*16.
__device__ __forceinline__ void gload16(const void* g, void* l) {
    __builtin_amdgcn_global_load_lds(
        (__attribute__((address_space(1))) void*)(uintptr_t)g,
        (__attribute__((address_space(3))) void*)(uint32_t)(uintptr_t)l,
        16, 0, 0);
}

// ---------------- prep kernels ----------------

__global__ __launch_bounds__(256) void cvt_bf16_kernel(
    const float4* __restrict__ in, us4* __restrict__ out, int n4) {
    int i = blockIdx.x * 256 + threadIdx.x;
    if (i >= n4) return;
    float4 v = in[i];
    us4 o; o[0] = f2bf(v.x); o[1] = f2bf(v.y); o[2] = f2bf(v.z); o[3] = f2bf(v.w);
    out[i] = o;
}

// in [R][C] fp32  ->  out [C][R] bf16   (64x64 LDS tile transpose)
__global__ __launch_bounds__(256) void transpose_bf16(
    const float* __restrict__ in, ushort_t* __restrict__ out, int R, int C) {
    __shared__ float t[64][65];
    int c0 = blockIdx.x * 64, r0 = blockIdx.y * 64;
    int cc = threadIdx.x & 63, rr = threadIdx.x >> 6;
#pragma unroll
    for (int i = 0; i < 16; ++i) {
        int r = i * 4 + rr;
        t[r][cc] = in[(size_t)(r0 + r) * C + c0 + cc];
    }
    __syncthreads();
#pragma unroll
    for (int i = 0; i < 16; ++i) {
        int r = i * 4 + rr;
        out[(size_t)(c0 + r) * R + r0 + cc] = f2bf(t[cc][r]);
    }
}

// rope table: [L][64] of (cos, sin)
__global__ __launch_bounds__(256) void rope_table_kernel(float2* __restrict__ rope) {
    int i = blockIdx.x * 256 + threadIdx.x;     // L*64 = 131072 exactly
    int l = i >> 6, j = i & 63;
    float inv = exp2f((float)j * -0.20762050593046f);  // 10000^(-j/64)
    float f = (float)l * inv;
    rope[i] = make_float2(cosf(f), sinf(f));
}

// ---------------- GEMM:  C[M][N] = A[M][K] * Bt[N][K]^T  (bf16 in, fp32 acc) ----------------

template <int EPI>
__global__ __launch_bounds__(256, 2)
void gemm_bt(const ushort_t* __restrict__ A, const ushort_t* __restrict__ Bt,
             int M, int N, int K,
             float* __restrict__ C,
             ushort_t* __restrict__ Qb, ushort_t* __restrict__ Kb,
             ushort_t* __restrict__ Vt, const float2* __restrict__ rope) {
    constexpr int MI = (EPI == 1) ? 2 : 4;
    constexpr int NI = (EPI == 1) ? 8 : 4;

    __shared__ __attribute__((aligned(16))) ushort_t ldsA[128 * 64];
    __shared__ __attribute__((aligned(16))) ushort_t ldsB[128 * 64];
    char* ldsAc = (char*)ldsA;
    char* ldsBc = (char*)ldsB;

    const int tid  = threadIdx.x;
    const int lane = tid & 63, wid = tid >> 6;
    const int lr = lane & 15, lg = lane >> 4;

    const int nbn = N >> 7;
    const int nwg = gridDim.x;
    const int bid = blockIdx.x;
    const int wg  = (bid & 7) * (nwg >> 3) + (bid >> 3);   // XCD-contiguous chunks
    const int bm  = wg / nbn, bn = wg % nbn;

    const int arow0 = (EPI == 1) ? wid * 32 : (wid >> 1) * 64;
    const int bcol0 = (EPI == 1) ? 0        : (wid & 1) * 64;

    const int colb = ((tid & 7) << 4) ^ (((tid >> 3) & 7) << 4);
    const int rowi = tid >> 3;                       // 0..31
    const char* Ap = (const char*)A + ((size_t)(bm * 128 + rowi) * K) * 2 + colb;
    const char* Bp = (const char*)Bt + ((size_t)(bn * 128 + rowi) * K) * 2 + colb;
    const size_t rstr = (size_t)32 * K * 2;
    char* ldA = ldsAc + wid * 1024;
    char* ldB = ldsBc + wid * 1024;

    f32x4 acc[MI][NI];
#pragma unroll
    for (int i = 0; i < MI; ++i)
#pragma unroll
        for (int j = 0; j < NI; ++j) acc[i][j] = (f32x4){0.f, 0.f, 0.f, 0.f};

    for (int k0 = 0; k0 < K; k0 += 64) {
#pragma unroll
        for (int r = 0; r < 4; ++r) {
            gload16(Ap + r * rstr + (size_t)k0 * 2, ldA + r * 4096);
            gload16(Bp + r * rstr + (size_t)k0 * 2, ldB + r * 4096);
        }
        __syncthreads();
#pragma unroll
        for (int kk = 0; kk < 2; ++kk) {
            bf16x8 af[MI], bfv[NI];
#pragma unroll
            for (int mi = 0; mi < MI; ++mi) {
                int row = arow0 + mi * 16 + lr;
                int off = (row << 7) + kk * 64 + lg * 16;
                off ^= (row & 7) << 4;
                af[mi] = *(const bf16x8*)(ldsAc + off);
            }
#pragma unroll
            for (int ni = 0; ni < NI; ++ni) {
                int row = bcol0 + ni * 16 + lr;
                int off = (row << 7) + kk * 64 + lg * 16;
                off ^= (row & 7) << 4;
                bfv[ni] = *(const bf16x8*)(ldsBc + off);
            }
#pragma unroll
            for (int mi = 0; mi < MI; ++mi)
#pragma unroll
                for (int ni = 0; ni < NI; ++ni)
                    acc[mi][ni] = __builtin_amdgcn_mfma_f32_16x16x32_bf16(
                        af[mi], bfv[ni], acc[mi][ni], 0, 0, 0);
        }
        __syncthreads();
    }

    if constexpr (EPI == 0) {
#pragma unroll
        for (int mi = 0; mi < MI; ++mi) {
            int gr0 = bm * 128 + arow0 + mi * 16 + lg * 4;
#pragma unroll
            for (int ni = 0; ni < NI; ++ni) {
                int gc = bn * 128 + bcol0 + ni * 16 + lr;
#pragma unroll
                for (int r = 0; r < 4; ++r)
                    C[(size_t)(gr0 + r) * N + gc] = acc[mi][ni][r];
            }
        }
    } else {
        const int which = bn >> 4, h = bn & 15;
#pragma unroll
        for (int mi = 0; mi < MI; ++mi) {
            int gr0 = bm * 128 + arow0 + mi * 16 + lg * 4;   // = b*L + l0 (4 consecutive l)
            int b = gr0 >> 11, l0 = gr0 & 2047;
            if (which == 2) {                                 // V -> [BH][D][L] (transposed)
#pragma unroll
                for (int ni = 0; ni < NI; ++ni) {
                    int d = ni * 16 + lr;
                    us4 pk;
#pragma unroll
                    for (int r = 0; r < 4; ++r) pk[r] = f2bf(acc[mi][ni][r]);
                    *(us4*)(Vt + ((size_t)(b * 16 + h) * 128 + d) * 2048 + l0) = pk;
                }
            } else {                                          // Q/K: rope, -> [BH][L][D]
                ushort_t* dst = (which == 0) ? Qb : Kb;
                const float sc = (which == 0) ? QK_SCALE : 1.0f;
#pragma unroll
                for (int ni = 0; ni < 4; ++ni) {
                    int j = ni * 16 + lr;                     // d < 64 ; pair at d+64 = frag ni+4
#pragma unroll
                    for (int r = 0; r < 4; ++r) {
                        float2 cs = rope[(size_t)(l0 + r) * 64 + j];
                        float x1 = acc[mi][ni][r], x2 = acc[mi][ni + 4][r];
                        size_t base = ((size_t)(b * 16 + h) * 2048 + (l0 + r)) * 128;
                        dst[base + j]      = f2bf((x1 * cs.x - x2 * cs.y) * sc);
                        dst[base + j + 64] = f2bf((x2 * cs.x + x1 * cs.y) * sc);
                    }
                }
            }
        }
    }
}

// ---------------- causal flash attention (swapped-operand, in-register softmax) ----------------
// Q,K: [BH][L][128] bf16 (Q pre-scaled); V^T: [BH][128][L] bf16; AO: [B][L][H*128] bf16.
// One wave per block, ONE 32-row slice per block (4096 blocks -> 16 waves/CU).
// Longest-slice-first dispatch order (rank 0 -> sl 63) kills the causal tail.
// V loads batched BEFORE softmax: their ~200-500cyc latency hides under softmax VALU.

__global__ __launch_bounds__(64, 3)
void attn_fwd(const ushort_t* __restrict__ Qb, const ushort_t* __restrict__ Kb,
              const ushort_t* __restrict__ Vt, ushort_t* __restrict__ AO) {
    constexpr int L = 2048;
    const int lane = threadIdx.x;
    const int q_l  = lane & 31;
    const int hi   = lane >> 5;

    // 4096 blocks: xcd = bid&7 (head affinity), hl = heads 0..7 on that xcd,
    // rank 0..63 -> slice sl = 63-rank (longest first in dispatch order).
    const int bid  = blockIdx.x;
    const int j    = bid >> 3;
    const int hl   = j & 7;
    const int rank = j >> 3;                    // 0..63
    const int head = (bid & 7) * 8 + hl;
    const int sl   = 63 - rank;
    const int q0   = sl * 32;

    const ushort_t* Qh = Qb + (size_t)head * L * 128;
    const ushort_t* Kh = Kb + (size_t)head * L * 128;
    const ushort_t* Vh = Vt + (size_t)head * 128 * L;
    const int b = head >> 4, h = head & 15;

    // Q^T B-frags hoisted: lane holds Q[q0+q_l][sb*16 + hi*8 + 0..7]
    bf16x8 qf[8];
#pragma unroll
    for (int sb = 0; sb < 8; ++sb)
        qf[sb] = *(const bf16x8*)(Qh + (size_t)(q0 + q_l) * 128 + sb * 16 + hi * 8);

    f32x16 o[4];
#pragma unroll
    for (int d0 = 0; d0 < 4; ++d0) o[d0] = (f32x16)(0.f);
    float m_ = -__builtin_inff(), l_ = 0.f;

    const int ntile = sl + 1;
    for (int t = 0; t < ntile; ++t) {
        const int k0 = t * 32;

        // ---- S^T = K * Q^T : two accumulator chains (halve dependent-MFMA depth) ----
        bf16x8 kf[8];
#pragma unroll
        for (int sb = 0; sb < 8; ++sb)
            kf[sb] = *(const bf16x8*)(Kh + (size_t)(k0 + q_l) * 128 + sb * 16 + hi * 8);
        f32x16 sa = (f32x16)(0.f), sb2 = (f32x16)(0.f);
#pragma unroll
        for (int sb = 0; sb < 8; sb += 2) {
            sa  = __builtin_amdgcn_mfma_f32_32x32x16_bf16(kf[sb],     qf[sb],     sa,  0, 0, 0);
            sb2 = __builtin_amdgcn_mfma_f32_32x32x16_bf16(kf[sb + 1], qf[sb + 1], sb2, 0, 0, 0);
        }
        f32x16 s = sa + sb2;

        // ---- V loads issued NOW (independent of softmax); consumed after it ----
        bf16x8 vf[8];
#pragma unroll
        for (int d0 = 0; d0 < 4; ++d0)
#pragma unroll
            for (int ks = 0; ks < 2; ++ks)
                vf[d0 * 2 + ks] = *(const bf16x8*)(Vh + (size_t)(d0 * 32 + q_l) * L + k0 + ks * 16 + hi * 8);

        // causal mask on the diagonal tile: k = k0 + crow(reg,hi), q = q0 + q_l, k0==q0
        if (t == ntile - 1) {
#pragma unroll
            for (int r = 0; r < 16; ++r) {
                int kk = (r & 3) + 8 * (r >> 2) + 4 * hi;
                if (kk > q_l) s[r] = NEG_BIG;
            }
        }

        // ---- in-register online softmax (lane owns q-row q0+q_l) ----
        float t8[8];
#pragma unroll
        for (int r = 0; r < 8; ++r) t8[r] = fmaxf(s[r], s[r + 8]);
#pragma unroll
        for (int r = 0; r < 4; ++r) t8[r] = fmaxf(t8[r], t8[r + 4]);
        float tmax = fmaxf(fmaxf(t8[0], t8[1]), fmaxf(t8[2], t8[3]));
        tmax = fmaxf(tmax, __shfl_xor(tmax, 32, 64));     // full 32-k row max

        if (!__all(tmax <= m_ + 8.f)) {                   // defer-max THR=8 (log2 units)
            float mn = fmaxf(m_, tmax);
            float alpha = exp2f(m_ - mn);
            m_ = mn;
            l_ *= alpha;
#pragma unroll
            for (int d0 = 0; d0 < 4; ++d0)
#pragma unroll
                for (int r = 0; r < 16; ++r) o[d0][r] *= alpha;
        }

        float p[16];
        float rs = 0.f;
#pragma unroll
        for (int r = 0; r < 16; ++r) { p[r] = exp2f(s[r] - m_); rs += p[r]; }
        rs += __shfl_xor(rs, 32, 64);
        l_ += rs;

        // ---- pack P -> bf16 pairs; assemble P^T B-frags via partner exchange ----
        unsigned int pk[8];
#pragma unroll
        for (int i = 0; i < 8; ++i) pk[i] = pk2bf(p[2 * i], p[2 * i + 1]);
        unsigned int po[8];
#pragma unroll
        for (int i = 0; i < 8; ++i) po[i] = __shfl_xor(pk[i], 32, 64);

        bf16x8 pf[2];
#pragma unroll
        for (int ks = 0; ks < 2; ++ks) {
            ui4 dw;
            dw[0] = hi ? po[ks * 4 + 2] : pk[ks * 4 + 0];
            dw[1] = hi ? po[ks * 4 + 3] : pk[ks * 4 + 1];
            dw[2] = hi ? pk[ks * 4 + 2] : po[ks * 4 + 0];
            dw[3] = hi ? pk[ks * 4 + 3] : po[ks * 4 + 1];
            pf[ks] = __builtin_bit_cast(bf16x8, dw);
        }

        // ---- O^T += V^T * P^T : loads already in flight; MFMAs back-to-back ----
#pragma unroll
        for (int d0 = 0; d0 < 4; ++d0)
#pragma unroll
            for (int ks = 0; ks < 2; ++ks)
                o[d0] = __builtin_amdgcn_mfma_f32_32x32x16_bf16(vf[d0 * 2 + ks], pf[ks], o[d0], 0, 0, 0);
    }

    // ---- epilogue: lane owns q-row q0+q_l entirely; d = d0*32 + (g*8 + hi*4 + 0..3) ----
    const float inv = 1.f / l_;
    const size_t rowbase = ((size_t)(b * 2048 + q0 + q_l)) * 2048 + h * 128;
#pragma unroll
    for (int d0 = 0; d0 < 4; ++d0)
#pragma unroll
        for (int g = 0; g < 4; ++g) {
            us4 v;
#pragma unroll
            for (int r = 0; r < 4; ++r) v[r] = f2bf(o[d0][g * 4 + r] * inv);
            *(us4*)(AO + rowbase + d0 * 32 + g * 8 + hi * 4) = v;
        }
}

// ---------------- launcher ----------------

extern "C" void kernel_launch(void* const* d_in, const int* in_sizes, int n_in,
                              void* d_out, int out_size, void* d_ws, size_t ws_size,
                              hipStream_t stream) {
    const float* x    = (const float*)d_in[0];   // [4,2048,2048]
    const float* Wqkv = (const float*)d_in[1];   // [2048,6144]
    const float* Wo   = (const float*)d_in[2];   // [2048,2048]
    float* out = (float*)d_out;                  // [4,2048,2048] fp32

    char* w = (char*)d_ws;
    ushort_t* xb   = (ushort_t*)(w);               // x bf16             33,554,432 B
    ushort_t* W1t  = (ushort_t*)(w + 33554432);    // Wqkv^T bf16        25,165,824 B
    ushort_t* Wot  = (ushort_t*)(w + 58720256);    // Wo^T bf16           8,388,608 B
    ushort_t* Qb   = (ushort_t*)(w + 67108864);    // Q roped [BH][L][D] 33,554,432 B
    ushort_t* Kbf  = (ushort_t*)(w + 100663296);   // K roped [BH][L][D] 33,554,432 B
    ushort_t* Vt   = (ushort_t*)(w + 134217728);   // V^T    [BH][D][L]  33,554,432 B
    ushort_t* AO   = (ushort_t*)(w + 167772160);   // attn out bf16      33,554,432 B
    float2*   rope = (float2*)(w + 201326592);     // [L][64] cos/sin     1,048,576 B

    cvt_bf16_kernel<<<16384, 256, 0, stream>>>((const float4*)x, (us4*)xb, 4194304);
    transpose_bf16<<<dim3(96, 32), 256, 0, stream>>>(Wqkv, W1t, 2048, 6144);
    transpose_bf16<<<dim3(32, 32), 256, 0, stream>>>(Wo, Wot, 2048, 2048);
    rope_table_kernel<<<512, 256, 0, stream>>>(rope);

    // qkv GEMM + fused rope/reshape epilogue
    gemm_bt<1><<<3072, 256, 0, stream>>>(xb, W1t, 8192, 6144, 2048,
                                         nullptr, Qb, Kbf, Vt, rope);
    // causal flash attention: 64 heads x 64 slices, one wave each, longest-first
    attn_fwd<<<4096, 64, 0, stream>>>(Qb, Kbf, Vt, AO);
    // output projection
    gemm_bt<0><<<1024, 256, 0, stream>>>(AO, Wot, 8192, 2048, 2048,
                                         out, nullptr, nullptr, nullptr, nullptr);
}

// Round 6
// 609.507 us; speedup vs baseline: 1.2532x; 1.0056x over previous
//
#include <hip/hip_runtime.h>
#include <hip/hip_bf16.h>
#include <stdint.h>

typedef unsigned short ushort_t;
typedef __bf16 bf16x8 __attribute__((ext_vector_type(8)));
typedef float    f32x4 __attribute__((ext_vector_type(4)));
typedef float   f32x16 __attribute__((ext_vector_type(16)));
typedef unsigned short us4 __attribute__((ext_vector_type(4)));
typedef unsigned int ui4 __attribute__((ext_vector_type(4)));

#define QK_SCALE 0.12751744f   /* log2(e) / sqrt(128) : folded into Q so softmax uses exp2 */
#define NEG_BIG  -1e30f

__device__ __forceinline__ unsigned short f2bf(float f) {
    union { float f; unsigned int u; } v; v.f = f;
    unsigned int u = v.u;
    return (unsigned short)((u + 0x7FFFu + ((u >> 16) & 1u)) >> 16);  // RNE
}

// HW packed convert: dst.lo = bf16(a), dst.hi = bf16(b)   (no builtin on gfx950)
__device__ __forceinline__ unsigned int pk2bf(float a, float b) {
    unsigned int r;
    asm("v_cvt_pk_bf16_f32 %0, %1, %2" : "=v"(r) : "v"(a), "v"(b));
    return r;
}

// async global->LDS, 16B per lane. LDS dest is wave-uniform base + lane*16.
__device__ __forceinline__ void gload16(const void* g, void* l) {
    __builtin_amdgcn_global_load_lds(
        (__attribute__((address_space(1))) void*)(uintptr_t)g,
        (__attribute__((address_space(3))) void*)(uint32_t)(uintptr_t)l,
        16, 0, 0);
}

// ---------------- prep kernels ----------------

__global__ __launch_bounds__(256) void cvt_bf16_kernel(
    const float4* __restrict__ in, us4* __restrict__ out, int n4) {
    int i = blockIdx.x * 256 + threadIdx.x;
    if (i >= n4) return;
    float4 v = in[i];
    us4 o; o[0] = f2bf(v.x); o[1] = f2bf(v.y); o[2] = f2bf(v.z); o[3] = f2bf(v.w);
    out[i] = o;
}

// in [R][C] fp32  ->  out [C][R] bf16   (64x64 LDS tile transpose)
__global__ __launch_bounds__(256) void transpose_bf16(
    const float* __restrict__ in, ushort_t* __restrict__ out, int R, int C) {
    __shared__ float t[64][65];
    int c0 = blockIdx.x * 64, r0 = blockIdx.y * 64;
    int cc = threadIdx.x & 63, rr = threadIdx.x >> 6;
#pragma unroll
    for (int i = 0; i < 16; ++i) {
        int r = i * 4 + rr;
        t[r][cc] = in[(size_t)(r0 + r) * C + c0 + cc];
    }
    __syncthreads();
#pragma unroll
    for (int i = 0; i < 16; ++i) {
        int r = i * 4 + rr;
        out[(size_t)(c0 + r) * R + r0 + cc] = f2bf(t[cc][r]);
    }
}

// rope table: [L][64] of (cos, sin)
__global__ __launch_bounds__(256) void rope_table_kernel(float2* __restrict__ rope) {
    int i = blockIdx.x * 256 + threadIdx.x;     // L*64 = 131072 exactly
    int l = i >> 6, j = i & 63;
    float inv = exp2f((float)j * -0.20762050593046f);  // 10000^(-j/64)
    float f = (float)l * inv;
    rope[i] = make_float2(cosf(f), sinf(f));
}

// ---------------- GEMM:  C[M][N] = A[M][K] * Bt[N][K]^T  (bf16 in, fp32 acc) ----------------

template <int EPI>
__global__ __launch_bounds__(256, 2)
void gemm_bt(const ushort_t* __restrict__ A, const ushort_t* __restrict__ Bt,
             int M, int N, int K,
             float* __restrict__ C,
             ushort_t* __restrict__ Qb, ushort_t* __restrict__ Kb,
             ushort_t* __restrict__ Vt, const float2* __restrict__ rope) {
    constexpr int MI = (EPI == 1) ? 2 : 4;
    constexpr int NI = (EPI == 1) ? 8 : 4;

    __shared__ __attribute__((aligned(16))) ushort_t ldsA[128 * 64];
    __shared__ __attribute__((aligned(16))) ushort_t ldsB[128 * 64];
    char* ldsAc = (char*)ldsA;
    char* ldsBc = (char*)ldsB;

    const int tid  = threadIdx.x;
    const int lane = tid & 63, wid = tid >> 6;
    const int lr = lane & 15, lg = lane >> 4;

    const int nbn = N >> 7;
    const int nwg = gridDim.x;
    const int bid = blockIdx.x;
    const int wg  = (bid & 7) * (nwg >> 3) + (bid >> 3);   // XCD-contiguous chunks
    const int bm  = wg / nbn, bn = wg % nbn;

    const int arow0 = (EPI == 1) ? wid * 32 : (wid >> 1) * 64;
    const int bcol0 = (EPI == 1) ? 0        : (wid & 1) * 64;

    const int colb = ((tid & 7) << 4) ^ (((tid >> 3) & 7) << 4);
    const int rowi = tid >> 3;                       // 0..31
    const char* Ap = (const char*)A + ((size_t)(bm * 128 + rowi) * K) * 2 + colb;
    const char* Bp = (const char*)Bt + ((size_t)(bn * 128 + rowi) * K) * 2 + colb;
    const size_t rstr = (size_t)32 * K * 2;
    char* ldA = ldsAc + wid * 1024;
    char* ldB = ldsBc + wid * 1024;

    f32x4 acc[MI][NI];
#pragma unroll
    for (int i = 0; i < MI; ++i)
#pragma unroll
        for (int j = 0; j < NI; ++j) acc[i][j] = (f32x4){0.f, 0.f, 0.f, 0.f};

    for (int k0 = 0; k0 < K; k0 += 64) {
#pragma unroll
        for (int r = 0; r < 4; ++r) {
            gload16(Ap + r * rstr + (size_t)k0 * 2, ldA + r * 4096);
            gload16(Bp + r * rstr + (size_t)k0 * 2, ldB + r * 4096);
        }
        __syncthreads();
#pragma unroll
        for (int kk = 0; kk < 2; ++kk) {
            bf16x8 af[MI], bfv[NI];
#pragma unroll
            for (int mi = 0; mi < MI; ++mi) {
                int row = arow0 + mi * 16 + lr;
                int off = (row << 7) + kk * 64 + lg * 16;
                off ^= (row & 7) << 4;
                af[mi] = *(const bf16x8*)(ldsAc + off);
            }
#pragma unroll
            for (int ni = 0; ni < NI; ++ni) {
                int row = bcol0 + ni * 16 + lr;
                int off = (row << 7) + kk * 64 + lg * 16;
                off ^= (row & 7) << 4;
                bfv[ni] = *(const bf16x8*)(ldsBc + off);
            }
#pragma unroll
            for (int mi = 0; mi < MI; ++mi)
#pragma unroll
                for (int ni = 0; ni < NI; ++ni)
                    acc[mi][ni] = __builtin_amdgcn_mfma_f32_16x16x32_bf16(
                        af[mi], bfv[ni], acc[mi][ni], 0, 0, 0);
        }
        __syncthreads();
    }

    if constexpr (EPI == 0) {
#pragma unroll
        for (int mi = 0; mi < MI; ++mi) {
            int gr0 = bm * 128 + arow0 + mi * 16 + lg * 4;
#pragma unroll
            for (int ni = 0; ni < NI; ++ni) {
                int gc = bn * 128 + bcol0 + ni * 16 + lr;
#pragma unroll
                for (int r = 0; r < 4; ++r)
                    C[(size_t)(gr0 + r) * N + gc] = acc[mi][ni][r];
            }
        }
    } else {
        const int which = bn >> 4, h = bn & 15;
#pragma unroll
        for (int mi = 0; mi < MI; ++mi) {
            int gr0 = bm * 128 + arow0 + mi * 16 + lg * 4;   // = b*L + l0 (4 consecutive l)
            int b = gr0 >> 11, l0 = gr0 & 2047;
            if (which == 2) {                                 // V -> [BH][D][L] (transposed)
#pragma unroll
                for (int ni = 0; ni < NI; ++ni) {
                    int d = ni * 16 + lr;
                    us4 pk;
#pragma unroll
                    for (int r = 0; r < 4; ++r) pk[r] = f2bf(acc[mi][ni][r]);
                    *(us4*)(Vt + ((size_t)(b * 16 + h) * 128 + d) * 2048 + l0) = pk;
                }
            } else {                                          // Q/K: rope, -> [BH][L][D]
                ushort_t* dst = (which == 0) ? Qb : Kb;
                const float sc = (which == 0) ? QK_SCALE : 1.0f;
#pragma unroll
                for (int ni = 0; ni < 4; ++ni) {
                    int j = ni * 16 + lr;                     // d < 64 ; pair at d+64 = frag ni+4
#pragma unroll
                    for (int r = 0; r < 4; ++r) {
                        float2 cs = rope[(size_t)(l0 + r) * 64 + j];
                        float x1 = acc[mi][ni][r], x2 = acc[mi][ni + 4][r];
                        size_t base = ((size_t)(b * 16 + h) * 2048 + (l0 + r)) * 128;
                        dst[base + j]      = f2bf((x1 * cs.x - x2 * cs.y) * sc);
                        dst[base + j + 64] = f2bf((x2 * cs.x + x1 * cs.y) * sc);
                    }
                }
            }
        }
    }
}

// ---------------- causal flash attention (swapped-operand, in-register softmax) ----------------
// Q,K: [BH][L][128] bf16 (Q pre-scaled); V^T: [BH][128][L] bf16; AO: [B][L][H*128] bf16.
// One wave per block, one 32-row slice per block; longest-slice-first dispatch.
// amdgpu_waves_per_eu(2,2): register-rich build (target 2 waves/SIMD, cap 256 VGPR) so
// qf stays resident and kf/vf load batches issue back-to-back (one latency wait per batch,
// not one per load). K(t+1) prefetched into registers during tile t.

__global__ __attribute__((amdgpu_flat_work_group_size(64, 64), amdgpu_waves_per_eu(2, 2)))
void attn_fwd(const ushort_t* __restrict__ Qb, const ushort_t* __restrict__ Kb,
              const ushort_t* __restrict__ Vt, ushort_t* __restrict__ AO) {
    constexpr int L = 2048;
    const int lane = threadIdx.x;
    const int q_l  = lane & 31;
    const int hi   = lane >> 5;

    // 4096 blocks: xcd = bid&7 (head affinity), hl = heads 0..7 on that xcd,
    // rank 0..63 -> slice sl = 63-rank (longest first in dispatch order).
    const int bid  = blockIdx.x;
    const int j    = bid >> 3;
    const int hl   = j & 7;
    const int rank = j >> 3;                    // 0..63
    const int head = (bid & 7) * 8 + hl;
    const int sl   = 63 - rank;
    const int q0   = sl * 32;

    const ushort_t* Qh = Qb + (size_t)head * L * 128;
    const ushort_t* Kh = Kb + (size_t)head * L * 128;
    const ushort_t* Vh = Vt + (size_t)head * 128 * L;
    const int b = head >> 4, h = head & 15;

    // Q^T B-frags hoisted: lane holds Q[q0+q_l][sb*16 + hi*8 + 0..7]
    bf16x8 qf[8];
#pragma unroll
    for (int sb = 0; sb < 8; ++sb)
        qf[sb] = *(const bf16x8*)(Qh + (size_t)(q0 + q_l) * 128 + sb * 16 + hi * 8);

    f32x16 o[4];
#pragma unroll
    for (int d0 = 0; d0 < 4; ++d0) o[d0] = (f32x16)(0.f);
    float m_ = -__builtin_inff(), l_ = 0.f;

    // K(0) preload
    bf16x8 kf[8];
#pragma unroll
    for (int sb = 0; sb < 8; ++sb)
        kf[sb] = *(const bf16x8*)(Kh + (size_t)q_l * 128 + sb * 16 + hi * 8);

    const int ntile = sl + 1;
    for (int t = 0; t < ntile; ++t) {
        const int k0 = t * 32;

        // ---- V loads for THIS tile issued first (consumed ~600 cyc later, after softmax) ----
        bf16x8 vf[8];
#pragma unroll
        for (int d0 = 0; d0 < 4; ++d0)
#pragma unroll
            for (int ks = 0; ks < 2; ++ks)
                vf[d0 * 2 + ks] = *(const bf16x8*)(Vh + (size_t)(d0 * 32 + q_l) * L + k0 + ks * 16 + hi * 8);

        // ---- S^T = K * Q^T : two accumulator chains (kf already in registers) ----
        f32x16 sa = (f32x16)(0.f), sb2 = (f32x16)(0.f);
#pragma unroll
        for (int sb = 0; sb < 8; sb += 2) {
            sa  = __builtin_amdgcn_mfma_f32_32x32x16_bf16(kf[sb],     qf[sb],     sa,  0, 0, 0);
            sb2 = __builtin_amdgcn_mfma_f32_32x32x16_bf16(kf[sb + 1], qf[sb + 1], sb2, 0, 0, 0);
        }
        f32x16 s = sa + sb2;

        // ---- K(t+1) prefetch: latency hides under softmax + PV of tile t ----
        if (t + 1 < ntile) {
            const int kn = k0 + 32;
#pragma unroll
            for (int sb = 0; sb < 8; ++sb)
                kf[sb] = *(const bf16x8*)(Kh + (size_t)(kn + q_l) * 128 + sb * 16 + hi * 8);
        }

        // causal mask on the diagonal tile: k = k0 + crow(reg,hi), q = q0 + q_l, k0==q0
        if (t == ntile - 1) {
#pragma unroll
            for (int r = 0; r < 16; ++r) {
                int kk = (r & 3) + 8 * (r >> 2) + 4 * hi;
                if (kk > q_l) s[r] = NEG_BIG;
            }
        }

        // ---- in-register online softmax (lane owns q-row q0+q_l) ----
        float t8[8];
#pragma unroll
        for (int r = 0; r < 8; ++r) t8[r] = fmaxf(s[r], s[r + 8]);
#pragma unroll
        for (int r = 0; r < 4; ++r) t8[r] = fmaxf(t8[r], t8[r + 4]);
        float tmax = fmaxf(fmaxf(t8[0], t8[1]), fmaxf(t8[2], t8[3]));
        tmax = fmaxf(tmax, __shfl_xor(tmax, 32, 64));     // full 32-k row max

        if (!__all(tmax <= m_ + 8.f)) {                   // defer-max THR=8 (log2 units)
            float mn = fmaxf(m_, tmax);
            float alpha = exp2f(m_ - mn);
            m_ = mn;
            l_ *= alpha;
#pragma unroll
            for (int d0 = 0; d0 < 4; ++d0)
#pragma unroll
                for (int r = 0; r < 16; ++r) o[d0][r] *= alpha;
        }

        float p[16];
        float rs = 0.f;
#pragma unroll
        for (int r = 0; r < 16; ++r) { p[r] = exp2f(s[r] - m_); rs += p[r]; }
        rs += __shfl_xor(rs, 32, 64);
        l_ += rs;

        // ---- pack P -> bf16 pairs (HW cvt_pk); assemble P^T B-frags via partner exchange ----
        unsigned int pk[8];
#pragma unroll
        for (int i = 0; i < 8; ++i) pk[i] = pk2bf(p[2 * i], p[2 * i + 1]);
        unsigned int po[8];
#pragma unroll
        for (int i = 0; i < 8; ++i) po[i] = __shfl_xor(pk[i], 32, 64);

        bf16x8 pf[2];
#pragma unroll
        for (int ks = 0; ks < 2; ++ks) {
            ui4 dw;
            dw[0] = hi ? po[ks * 4 + 2] : pk[ks * 4 + 0];
            dw[1] = hi ? po[ks * 4 + 3] : pk[ks * 4 + 1];
            dw[2] = hi ? pk[ks * 4 + 2] : po[ks * 4 + 0];
            dw[3] = hi ? pk[ks * 4 + 3] : po[ks * 4 + 1];
            pf[ks] = __builtin_bit_cast(bf16x8, dw);
        }

        // ---- O^T += V^T * P^T : vf long in flight; MFMAs back-to-back ----
#pragma unroll
        for (int d0 = 0; d0 < 4; ++d0)
#pragma unroll
            for (int ks = 0; ks < 2; ++ks)
                o[d0] = __builtin_amdgcn_mfma_f32_32x32x16_bf16(vf[d0 * 2 + ks], pf[ks], o[d0], 0, 0, 0);
    }

    // ---- epilogue: lane owns q-row q0+q_l entirely; d = d0*32 + (g*8 + hi*4 + 0..3) ----
    const float inv = 1.f / l_;
    const size_t rowbase = ((size_t)(b * 2048 + q0 + q_l)) * 2048 + h * 128;
#pragma unroll
    for (int d0 = 0; d0 < 4; ++d0)
#pragma unroll
        for (int g = 0; g < 4; ++g) {
            us4 v;
#pragma unroll
            for (int r = 0; r < 4; ++r) v[r] = f2bf(o[d0][g * 4 + r] * inv);
            *(us4*)(AO + rowbase + d0 * 32 + g * 8 + hi * 4) = v;
        }
}

// ---------------- launcher ----------------

extern "C" void kernel_launch(void* const* d_in, const int* in_sizes, int n_in,
                              void* d_out, int out_size, void* d_ws, size_t ws_size,
                              hipStream_t stream) {
    const float* x    = (const float*)d_in[0];   // [4,2048,2048]
    const float* Wqkv = (const float*)d_in[1];   // [2048,6144]
    const float* Wo   = (const float*)d_in[2];   // [2048,2048]
    float* out = (float*)d_out;                  // [4,2048,2048] fp32

    char* w = (char*)d_ws;
    ushort_t* xb   = (ushort_t*)(w);               // x bf16             33,554,432 B
    ushort_t* W1t  = (ushort_t*)(w + 33554432);    // Wqkv^T bf16        25,165,824 B
    ushort_t* Wot  = (ushort_t*)(w + 58720256);    // Wo^T bf16           8,388,608 B
    ushort_t* Qb   = (ushort_t*)(w + 67108864);    // Q roped [BH][L][D] 33,554,432 B
    ushort_t* Kbf  = (ushort_t*)(w + 100663296);   // K roped [BH][L][D] 33,554,432 B
    ushort_t* Vt   = (ushort_t*)(w + 134217728);   // V^T    [BH][D][L]  33,554,432 B
    ushort_t* AO   = (ushort_t*)(w + 167772160);   // attn out bf16      33,554,432 B
    float2*   rope = (float2*)(w + 201326592);     // [L][64] cos/sin     1,048,576 B

    cvt_bf16_kernel<<<16384, 256, 0, stream>>>((const float4*)x, (us4*)xb, 4194304);
    transpose_bf16<<<dim3(96, 32), 256, 0, stream>>>(Wqkv, W1t, 2048, 6144);
    transpose_bf16<<<dim3(32, 32), 256, 0, stream>>>(Wo, Wot, 2048, 2048);
    rope_table_kernel<<<512, 256, 0, stream>>>(rope);

    // qkv GEMM + fused rope/reshape epilogue
    gemm_bt<1><<<3072, 256, 0, stream>>>(xb, W1t, 8192, 6144, 2048,
                                         nullptr, Qb, Kbf, Vt, rope);
    // causal flash attention: 64 heads x 64 slices, one wave each, longest-first
    attn_fwd<<<4096, 64, 0, stream>>>(Qb, Kbf, Vt, AO);
    // output projection
    gemm_bt<0><<<1024, 256, 0, stream>>>(AO, Wot, 8192, 2048, 2048,
                                         out, nullptr, nullptr, nullptr, nullptr);
}